// Round 9
// baseline (270.605 us; speedup 1.0000x reference)
//
#include <hip/hip_runtime.h>
#include <hip/hip_bf16.h>

#define B_SZ 100000
#define NTOT 200000
#define NN   1000000
#define DIM  128

#define NB_CLAIM  782               // ceil(2e5/256)
#define NB_WFRAG  32
#define NB_PREP   (NB_CLAIM + NB_WFRAG + 1)

#define TILES     62500             // 1e6 nodes / 16 per wave-tile
#define GRID_MAIN 512               // 2 blocks/CU (64 KB LDS each)
#define BLK_MAIN  768               // 12 waves -> 24 waves/CU (6/SIMD)
#define WPB       12
#define WAVES_TOT (GRID_MAIN * WPB) // 6144 wave slots

typedef short bf16x8 __attribute__((ext_vector_type(8)));
typedef float f32x4  __attribute__((ext_vector_type(4)));

__device__ __forceinline__ short f2bf(float f) {
    union { float f; unsigned u; } v; v.f = f;
    unsigned u = v.u;
    u += 0x7fffu + ((u >> 16) & 1u);
    return (short)(u >> 16);
}

// ---------------- launch 2: claim || weight packing || bias ----------------
//  owner[node] = max(code): src codes [0,B), dst [B,2B) -> dst beats src,
//  later index beats earlier -> numpy sequential scatter semantics.
//  PA[k][n] = W_node[n][k] + (k==n)            (applied to prev)
//  PQ[k][n] = sum_m W_node[n][m]*W_nig[m][k]   (applied to nbr)
//  cvec[n]  = b_node[n] + sum_k b_nig[k]*W_node[n][k]
// B-frag layout (16x16x32 bf16): frag (kc,nc), lane l holds
//   col n = nc*16 + (l&15), k = kc*32 + (l>>4)*8 + i, i=0..7
__global__ __launch_bounds__(256) void k_prep(
        const int* __restrict__ src, const int* __restrict__ dst,
        int* __restrict__ owner,
        const float* __restrict__ Wnig, const float* __restrict__ bnig,
        const float* __restrict__ Wnode, const float* __restrict__ bnode,
        short* __restrict__ PA, short* __restrict__ PQ,
        float* __restrict__ cvec) {
    int b = blockIdx.x, t = threadIdx.x;
    if (b < NB_CLAIM) {
        int i = b * 256 + t;
        if (i < NTOT) {
            int node = (i < B_SZ) ? src[i] : dst[i - B_SZ];
            atomicMax(&owner[node], i);
        }
    } else if (b < NB_CLAIM + NB_WFRAG) {
        int b2 = b - NB_CLAIM;             // fragment index kc*8+nc
        int lane = t & 63, ig = t >> 6;    // ig 0..3 -> i = 2*ig, 2*ig+1
        int kc = b2 >> 3, nc = b2 & 7;
        int n = nc * 16 + (lane & 15);
        int kbase = kc * 32 + (lane >> 4) * 8;
        int fo = (b2 * 64 + lane) * 8;
        for (int ii = 0; ii < 2; ++ii) {
            int i = ig * 2 + ii;
            int k = kbase + i;
            float a = Wnode[n * DIM + k] + (k == n ? 1.0f : 0.0f);
            PA[fo + i] = f2bf(a);
            float q = 0.f;
            for (int m = 0; m < DIM; ++m) q += Wnode[n * DIM + m] * Wnig[m * DIM + k];
            PQ[fo + i] = f2bf(q);
        }
    } else {
        if (t < DIM) {
            float c = bnode[t];
            for (int k = 0; k < DIM; ++k) c += bnig[k] * Wnode[t * DIM + k];
            cvec[t] = c;
        }
    }
}

// ---------------- launch 3: node-ordered fused update+copy ----------------
// v1 structure (benched 252.7 us) + owner prefetch, at 12 waves/block:
// 2 blocks/CU (LDS-limited) now carry 24 waves/CU instead of 16.
// __launch_bounds__(768,6) pins VGPR <= 85 (v1 used 76 -> no spill).
__global__ __launch_bounds__(BLK_MAIN, 6) void k_node(
        const float* __restrict__ prev,
        const float* __restrict__ nsrc, const float* __restrict__ ndst,
        const int* __restrict__ owner,
        const short* __restrict__ PA, const short* __restrict__ PQ,
        const float* __restrict__ cvec,
        float* __restrict__ out) {
    __shared__ __align__(16) short lA[32 * 64 * 8];   // 32 KB
    __shared__ __align__(16) short lQ[32 * 64 * 8];   // 32 KB
    int tid = threadIdx.x;
    {
        const float4* gA = (const float4*)PA;
        const float4* gQ = (const float4*)PQ;
        float4* sA = (float4*)lA;
        float4* sQ = (float4*)lQ;
        for (int i = tid; i < 2048; i += BLK_MAIN) { sA[i] = gA[i]; sQ[i] = gQ[i]; }
    }
    __syncthreads();

    int wave = tid >> 6, lane = tid & 63;
    int wid = blockIdx.x * WPB + wave;
    int myrow = lane & 15;
    int koff = (lane >> 4) * 8;
    int col0 = lane & 15;
    int rbase = (lane >> 4) * 4;

    // bias slice: constant per lane across tiles
    float cv[8];
#pragma unroll
    for (int nc = 0; nc < 8; ++nc) cv[nc] = cvec[nc * 16 + col0];

    int t = wid;
    if (t >= TILES) return;
    int o_cur = owner[t * 16 + myrow];          // prologue owner fetch

    for (; t < TILES; t += WAVES_TOT) {
        int tn = t + WAVES_TOT;
        int o_nxt = (tn < TILES) ? owner[tn * 16 + myrow] : -1;  // prefetch

        int nbase = t * 16;
        int my_owner = o_cur;
        unsigned mask16 = (unsigned)(__ballot(my_owner >= 0) & 0xFFFFu);

        if (mask16) {
            const float* prow = prev + (size_t)(nbase + myrow) * DIM;
            const float* nrow = prow;  // dummy init
            if (my_owner >= 0) {
                bool is_src = my_owner < B_SZ;
                int bi = is_src ? my_owner : my_owner - B_SZ;
                nrow = (is_src ? nsrc : ndst) + (size_t)bi * DIM;
            }
            f32x4 acc[8];
#pragma unroll
            for (int nc = 0; nc < 8; ++nc) acc[nc] = (f32x4){0.f, 0.f, 0.f, 0.f};

#pragma unroll
            for (int kc = 0; kc < 4; ++kc) {
                int k0 = kc * 32 + koff;
                bf16x8 aP = (bf16x8){0,0,0,0,0,0,0,0};
                bf16x8 aN = (bf16x8){0,0,0,0,0,0,0,0};
                if (my_owner >= 0) {
                    float4 p0 = *(const float4*)(prow + k0);
                    float4 p1 = *(const float4*)(prow + k0 + 4);
                    float4 n0 = *(const float4*)(nrow + k0);
                    float4 n1 = *(const float4*)(nrow + k0 + 4);
                    aP[0]=f2bf(p0.x); aP[1]=f2bf(p0.y); aP[2]=f2bf(p0.z); aP[3]=f2bf(p0.w);
                    aP[4]=f2bf(p1.x); aP[5]=f2bf(p1.y); aP[6]=f2bf(p1.z); aP[7]=f2bf(p1.w);
                    aN[0]=f2bf(n0.x); aN[1]=f2bf(n0.y); aN[2]=f2bf(n0.z); aN[3]=f2bf(n0.w);
                    aN[4]=f2bf(n1.x); aN[5]=f2bf(n1.y); aN[6]=f2bf(n1.z); aN[7]=f2bf(n1.w);
                }
#pragma unroll
                for (int nc = 0; nc < 8; ++nc) {
                    int fo = ((kc * 8 + nc) * 64 + lane) * 8;
                    bf16x8 bA = *(const bf16x8*)(lA + fo);
                    bf16x8 bQ = *(const bf16x8*)(lQ + fo);
                    acc[nc] = __builtin_amdgcn_mfma_f32_16x16x32_bf16(aP, bA, acc[nc], 0, 0, 0);
                    acc[nc] = __builtin_amdgcn_mfma_f32_16x16x32_bf16(aN, bQ, acc[nc], 0, 0, 0);
                }
            }
            // epilogue: touched rows from acc (D: col = l&15, row = (l>>4)*4 + r)
#pragma unroll
            for (int r = 0; r < 4; ++r) {
                int rt = rbase + r;
                if ((mask16 >> rt) & 1u) {
                    float* orow = out + (size_t)(nbase + rt) * DIM;
#pragma unroll
                    for (int nc = 0; nc < 8; ++nc)
                        orow[nc * 16 + col0] = acc[nc][r] + cv[nc];
                }
            }
        }

        // untouched rows: coalesced copy, two rows per iteration (1 KB/instr)
        unsigned um = (~mask16) & 0xFFFFu;
        while (um) {
            int r0 = __builtin_ctz(um); um &= um - 1;
            int r1 = -1;
            if (um) { r1 = __builtin_ctz(um); um &= um - 1; }
            int r = (lane < 32) ? r0 : r1;
            if (r >= 0) {
                const float4* s4 = (const float4*)(prev + (size_t)(nbase + r) * DIM);
                float4* d4 = (float4*)(out + (size_t)(nbase + r) * DIM);
                d4[lane & 31] = s4[lane & 31];
            }
        }
        o_cur = o_nxt;
    }
}

extern "C" void kernel_launch(void* const* d_in, const int* in_sizes, int n_in,
                              void* d_out, int out_size, void* d_ws, size_t ws_size,
                              hipStream_t stream) {
    const int*   src  = (const int*)d_in[0];
    const int*   dst  = (const int*)d_in[1];
    const float* prev = (const float*)d_in[2];
    const float* nsrc = (const float*)d_in[3];
    const float* ndst = (const float*)d_in[4];
    const float* Wnig = (const float*)d_in[5];
    const float* bnig = (const float*)d_in[6];
    const float* Wnode = (const float*)d_in[7];
    const float* bnode = (const float*)d_in[8];
    float* out = (float*)d_out;

    const size_t OWNER_B = (size_t)NN * 4;
    const size_t PA_B = 32 * 64 * 8 * 2;     // 32 KB each
    if (ws_size < OWNER_B + 2 * PA_B + 512) return;
    char* ws = (char*)d_ws;
    int*   owner = (int*)ws;
    short* PA = (short*)(ws + OWNER_B);
    short* PQ = (short*)(ws + OWNER_B + PA_B);
    float* cvec = (float*)(ws + OWNER_B + 2 * PA_B);

    hipMemsetAsync(owner, 0xFF, OWNER_B, stream);     // owner[i] = -1
    k_prep<<<NB_PREP, 256, 0, stream>>>(
        src, dst, owner, Wnig, bnig, Wnode, bnode, PA, PQ, cvec);
    k_node<<<GRID_MAIN, BLK_MAIN, 0, stream>>>(
        prev, nsrc, ndst, owner, PA, PQ, cvec, out);
}

// Round 10
// 257.305 us; speedup vs baseline: 1.0517x; 1.0517x over previous
//
#include <hip/hip_runtime.h>
#include <hip/hip_bf16.h>

#define B_SZ 100000
#define NTOT 200000
#define NN   1000000
#define DIM  128

#define NB_CLAIM  782               // ceil(2e5/256)
#define NB_WFRAG  32
#define NB_PREP   (NB_CLAIM + NB_WFRAG + 1)

#define TILES     62500             // 1e6 nodes / 16 per wave-tile
#define GRID_MAIN 256               // 1 block/CU (132 KB LDS)
#define BLK_MAIN  1024              // 16 waves -> 16 waves/CU (4/SIMD), as v1
#define WPB       16
#define WAVES_TOT (GRID_MAIN * WPB) // 4096 wave slots
#define SSTRIDE   272               // staged row bytes: 256 + 16 pad (16-aligned)

typedef short bf16x8 __attribute__((ext_vector_type(8)));
typedef float f32x4  __attribute__((ext_vector_type(4)));

__device__ __forceinline__ short f2bf(float f) {
    union { float f; unsigned u; } v; v.f = f;
    unsigned u = v.u;
    u += 0x7fffu + ((u >> 16) & 1u);
    return (short)(u >> 16);
}

__device__ __forceinline__ unsigned pk2(float a, float b) {
    return (unsigned)(unsigned short)f2bf(a) | ((unsigned)(unsigned short)f2bf(b) << 16);
}

// ---------------- launch 2: claim || weight packing || bias ----------------
//  owner[node] = max(code): src codes [0,B), dst [B,2B) -> dst beats src,
//  later index beats earlier -> numpy sequential scatter semantics.
//  PA[k][n] = W_node[n][k] + (k==n)            (applied to prev)
//  PQ[k][n] = sum_m W_node[n][m]*W_nig[m][k]   (applied to nbr)
//  cvec[n]  = b_node[n] + sum_k b_nig[k]*W_node[n][k]
// B-frag layout (16x16x32 bf16): frag (kc,nc), lane l holds
//   col n = nc*16 + (l&15), k = kc*32 + (l>>4)*8 + i, i=0..7
__global__ __launch_bounds__(256) void k_prep(
        const int* __restrict__ src, const int* __restrict__ dst,
        int* __restrict__ owner,
        const float* __restrict__ Wnig, const float* __restrict__ bnig,
        const float* __restrict__ Wnode, const float* __restrict__ bnode,
        short* __restrict__ PA, short* __restrict__ PQ,
        float* __restrict__ cvec) {
    int b = blockIdx.x, t = threadIdx.x;
    if (b < NB_CLAIM) {
        int i = b * 256 + t;
        if (i < NTOT) {
            int node = (i < B_SZ) ? src[i] : dst[i - B_SZ];
            atomicMax(&owner[node], i);
        }
    } else if (b < NB_CLAIM + NB_WFRAG) {
        int b2 = b - NB_CLAIM;             // fragment index kc*8+nc
        int lane = t & 63, ig = t >> 6;    // ig 0..3 -> i = 2*ig, 2*ig+1
        int kc = b2 >> 3, nc = b2 & 7;
        int n = nc * 16 + (lane & 15);
        int kbase = kc * 32 + (lane >> 4) * 8;
        int fo = (b2 * 64 + lane) * 8;
        for (int ii = 0; ii < 2; ++ii) {
            int i = ig * 2 + ii;
            int k = kbase + i;
            float a = Wnode[n * DIM + k] + (k == n ? 1.0f : 0.0f);
            PA[fo + i] = f2bf(a);
            float q = 0.f;
            for (int m = 0; m < DIM; ++m) q += Wnode[n * DIM + m] * Wnig[m * DIM + k];
            PQ[fo + i] = f2bf(q);
        }
    } else {
        if (t < DIM) {
            float c = bnode[t];
            for (int k = 0; k < DIM; ++k) c += bnig[k] * Wnode[t * DIM + k];
            cvec[t] = c;
        }
    }
}

// ---------------- launch 3: node-ordered fused update+copy ----------------
// Per wave-tile (16 nodes):
//   1. issue nbr gather (longest latency) for touched lanes
//   2. unconditional LINEAR load of 16x128 prev tile (8 x 1KB coalesced)
//   3. stage tile to wave-private LDS as bf16 (single prev read, both uses)
//   4. masked copy-stores from registers (untouched rows)
//   5. MFMA: A-frag from LDS stage, nbr from regs; epilogue masked stores
// 1 block/CU: 64KB weights + 68KB stage = 132KB LDS, 16 waves/CU (as v1).
__global__ __launch_bounds__(BLK_MAIN, 4) void k_node(
        const float* __restrict__ prev,
        const float* __restrict__ nsrc, const float* __restrict__ ndst,
        const int* __restrict__ owner,
        const short* __restrict__ PA, const short* __restrict__ PQ,
        const float* __restrict__ cvec,
        float* __restrict__ out) {
    __shared__ __align__(16) short lA[32 * 64 * 8];     // 32 KB
    __shared__ __align__(16) short lQ[32 * 64 * 8];     // 32 KB
    __shared__ __align__(16) char  stg[WPB * 16 * SSTRIDE];  // 68 KB
    int tid = threadIdx.x;
    {
        const float4* gA = (const float4*)PA;
        const float4* gQ = (const float4*)PQ;
        float4* sA = (float4*)lA;
        float4* sQ = (float4*)lQ;
        for (int i = tid; i < 2048; i += BLK_MAIN) { sA[i] = gA[i]; sQ[i] = gQ[i]; }
    }
    __syncthreads();

    int wave = tid >> 6, lane = tid & 63;
    int wid = blockIdx.x * WPB + wave;
    int p     = lane >> 5;          // row parity for linear load
    int c     = lane & 31;          // f32x4 chunk within row
    int koff  = (lane >> 4) * 8;    // A-frag float offset
    int col0  = lane & 15;          // D-frag col
    int rbase = (lane >> 4) * 4;    // D-frag row base
    char* wstg = stg + wave * (16 * SSTRIDE);
    // A-frag read base: row = lane&15, byte = row*SSTRIDE + (l>>4)*16 (+kc*64)
    const char* ard = wstg + (lane & 15) * SSTRIDE + (lane >> 4) * 16;

    float cv[8];
#pragma unroll
    for (int nc = 0; nc < 8; ++nc) cv[nc] = cvec[nc * 16 + col0];

    int t = wid;
    if (t >= TILES) return;
    int o_cur = owner[t * 16 + (lane & 15)];    // prologue owner fetch

    const f32x4 z = (f32x4){0.f, 0.f, 0.f, 0.f};

    for (; t < TILES; t += WAVES_TOT) {
        int tn = t + WAVES_TOT;
        int o_nxt = (tn < TILES) ? owner[tn * 16 + (lane & 15)] : -1;  // prefetch

        int nbase = t * 16;
        bool touched = o_cur >= 0;
        unsigned mask16 = (unsigned)(__ballot(touched) & 0xFFFFu);

        // 1) nbr gather first (random, longest latency; consumed last)
        f32x4 nb[8];
#pragma unroll
        for (int i = 0; i < 8; ++i) nb[i] = z;
        if (touched) {
            bool is_src = o_cur < B_SZ;
            int bi = is_src ? o_cur : o_cur - B_SZ;
            const float* nrow = (is_src ? nsrc : ndst) + (size_t)bi * DIM + koff;
#pragma unroll
            for (int kc = 0; kc < 4; ++kc) {
                nb[2*kc]   = *(const f32x4*)(nrow + kc * 32);
                nb[2*kc+1] = *(const f32x4*)(nrow + kc * 32 + 4);
            }
        }

        // 2) linear unconditional prev tile read: v[j] = row 2j+p, chunk c
        const f32x4* p4 = (const f32x4*)(prev + (size_t)nbase * DIM);
        f32x4 v[8];
#pragma unroll
        for (int j = 0; j < 8; ++j) v[j] = p4[j * 64 + lane];

        // 3) stage to LDS as bf16 (only needed if any row touched)
        if (mask16) {
#pragma unroll
            for (int j = 0; j < 8; ++j) {
                int row = 2 * j + p;
                uint2 w = make_uint2(pk2(v[j][0], v[j][1]), pk2(v[j][2], v[j][3]));
                *(uint2*)(wstg + row * SSTRIDE + c * 8) = w;
            }
        }

        // 4) masked copy stores (untouched rows), straight from registers
        f32x4* o4 = (f32x4*)(out + (size_t)nbase * DIM);
#pragma unroll
        for (int j = 0; j < 8; ++j) {
            int row = 2 * j + p;
            if (!((mask16 >> row) & 1u)) o4[j * 64 + lane] = v[j];
        }

        // 5) MFMA from LDS stage + nbr regs
        if (mask16) {
            f32x4 acc[8];
#pragma unroll
            for (int nc = 0; nc < 8; ++nc) acc[nc] = z;
#pragma unroll
            for (int kc = 0; kc < 4; ++kc) {
                bf16x8 aP = *(const bf16x8*)(ard + kc * 64);
                bf16x8 aN;
                aN[0]=f2bf(nb[2*kc][0]); aN[1]=f2bf(nb[2*kc][1]);
                aN[2]=f2bf(nb[2*kc][2]); aN[3]=f2bf(nb[2*kc][3]);
                aN[4]=f2bf(nb[2*kc+1][0]); aN[5]=f2bf(nb[2*kc+1][1]);
                aN[6]=f2bf(nb[2*kc+1][2]); aN[7]=f2bf(nb[2*kc+1][3]);
#pragma unroll
                for (int nc = 0; nc < 8; ++nc) {
                    int fo = ((kc * 8 + nc) * 64 + lane) * 8;
                    bf16x8 bA = *(const bf16x8*)(lA + fo);
                    bf16x8 bQ = *(const bf16x8*)(lQ + fo);
                    acc[nc] = __builtin_amdgcn_mfma_f32_16x16x32_bf16(aP, bA, acc[nc], 0, 0, 0);
                    acc[nc] = __builtin_amdgcn_mfma_f32_16x16x32_bf16(aN, bQ, acc[nc], 0, 0, 0);
                }
            }
            // epilogue: touched rows (D: col = l&15, row = (l>>4)*4 + r)
#pragma unroll
            for (int r = 0; r < 4; ++r) {
                int rt = rbase + r;
                if ((mask16 >> rt) & 1u) {
                    float* orow = out + (size_t)(nbase + rt) * DIM;
#pragma unroll
                    for (int nc = 0; nc < 8; ++nc)
                        orow[nc * 16 + col0] = acc[nc][r] + cv[nc];
                }
            }
        }
        o_cur = o_nxt;
    }
}

extern "C" void kernel_launch(void* const* d_in, const int* in_sizes, int n_in,
                              void* d_out, int out_size, void* d_ws, size_t ws_size,
                              hipStream_t stream) {
    const int*   src  = (const int*)d_in[0];
    const int*   dst  = (const int*)d_in[1];
    const float* prev = (const float*)d_in[2];
    const float* nsrc = (const float*)d_in[3];
    const float* ndst = (const float*)d_in[4];
    const float* Wnig = (const float*)d_in[5];
    const float* bnig = (const float*)d_in[6];
    const float* Wnode = (const float*)d_in[7];
    const float* bnode = (const float*)d_in[8];
    float* out = (float*)d_out;

    const size_t OWNER_B = (size_t)NN * 4;
    const size_t PA_B = 32 * 64 * 8 * 2;     // 32 KB each
    if (ws_size < OWNER_B + 2 * PA_B + 512) return;
    char* ws = (char*)d_ws;
    int*   owner = (int*)ws;
    short* PA = (short*)(ws + OWNER_B);
    short* PQ = (short*)(ws + OWNER_B + PA_B);
    float* cvec = (float*)(ws + OWNER_B + 2 * PA_B);

    hipMemsetAsync(owner, 0xFF, OWNER_B, stream);     // owner[i] = -1
    k_prep<<<NB_PREP, 256, 0, stream>>>(
        src, dst, owner, Wnig, bnig, Wnode, bnode, PA, PQ, cvec);
    k_node<<<GRID_MAIN, BLK_MAIN, 0, stream>>>(
        prev, nsrc, ndst, owner, PA, PQ, cvec, out);
}